// Round 1
// baseline (699.070 us; speedup 1.0000x reference)
//
#include <hip/hip_runtime.h>
#include <hip/hip_bf16.h>
#include <math.h>

typedef __hip_bfloat16 bf16;
typedef float f32x4 __attribute__((ext_vector_type(4)));
typedef short short8 __attribute__((ext_vector_type(8)));
typedef unsigned short u16x4 __attribute__((ext_vector_type(4)));
typedef unsigned short u16x8 __attribute__((ext_vector_type(8)));

#define AS1 __attribute__((address_space(1)))
#define AS3 __attribute__((address_space(3)))

__device__ __forceinline__ void gload16(const void* g, void* l) {
  __builtin_amdgcn_global_load_lds((const AS1 unsigned int*)g, (AS3 unsigned int*)l, 16, 0, 0);
}
__device__ __forceinline__ float b2f(unsigned short u) {
  union { unsigned int i; float f; } c; c.i = ((unsigned int)u) << 16; return c.f;
}
__device__ __forceinline__ unsigned short f2b(float f) {
  bf16 h = __float2bfloat16(f);
  unsigned short s; __builtin_memcpy(&s, &h, 2); return s;
}
__device__ __forceinline__ f32x4 mfma16(short8 a, short8 b, f32x4 c) {
  return __builtin_amdgcn_mfma_f32_16x16x32_bf16(a, b, c, 0, 0, 0);
}

// ---------------- LayerNorm: f32 in -> bf16 out, one block per 1024-wide row ----------------
__global__ __launch_bounds__(256) void ln_kernel(
    const float* __restrict__ X, const float* __restrict__ G,
    const float* __restrict__ Bb, unsigned short* __restrict__ Y) {
  __shared__ float red[8];
  const size_t row = blockIdx.x;
  const int tid = threadIdx.x;
  f32x4 v = *(const f32x4*)&X[row * 1024 + tid * 4];
  float s = 0.f, sq = 0.f;
#pragma unroll
  for (int j = 0; j < 4; ++j) { s += v[j]; sq += v[j] * v[j]; }
#pragma unroll
  for (int o = 1; o < 64; o <<= 1) { s += __shfl_xor(s, o); sq += __shfl_xor(sq, o); }
  if ((tid & 63) == 0) { red[tid >> 6] = s; red[4 + (tid >> 6)] = sq; }
  __syncthreads();
  s = red[0] + red[1] + red[2] + red[3];
  sq = red[4] + red[5] + red[6] + red[7];
  const float mean = s * (1.f / 1024.f);
  const float var = sq * (1.f / 1024.f) - mean * mean;
  const float inv = 1.f / sqrtf(var + 1e-5f);
  f32x4 gv = *(const f32x4*)&G[tid * 4];
  f32x4 bv = *(const f32x4*)&Bb[tid * 4];
  u16x4 ov;
#pragma unroll
  for (int j = 0; j < 4; ++j) ov[j] = f2b((v[j] - mean) * inv * gv[j] + bv[j]);
  *(u16x4*)&Y[row * 1024 + tid * 4] = ov;
}

// ---------------- Weight transpose: f32 src[K][N] -> bf16 dst[n][dld] (+doff) ----------------
__global__ __launch_bounds__(256) void transpose_w(
    const float* __restrict__ S, unsigned short* __restrict__ D,
    int N, int dld, int doff) {
  __shared__ __attribute__((aligned(16))) unsigned short t[64][72];
  const int k0 = blockIdx.x * 64, n0 = blockIdx.y * 64;
  const int tid = threadIdx.x;
#pragma unroll
  for (int i = 0; i < 2; ++i) {
    int c = i * 256 + tid;
    int row = c >> 3, c8 = c & 7;
    f32x4 a = *(const f32x4*)&S[(size_t)(k0 + row) * N + n0 + c8 * 8];
    f32x4 b = *(const f32x4*)&S[(size_t)(k0 + row) * N + n0 + c8 * 8 + 4];
    u16x8 o;
#pragma unroll
    for (int j = 0; j < 4; ++j) { o[j] = f2b(a[j]); o[4 + j] = f2b(b[j]); }
    *(u16x8*)&t[row][c8 * 8] = o;
  }
  __syncthreads();
#pragma unroll
  for (int i = 0; i < 2; ++i) {
    int c = i * 256 + tid;
    int nrow = c >> 3, k8 = c & 7;
    u16x8 o;
#pragma unroll
    for (int j = 0; j < 8; ++j) o[j] = t[k8 * 8 + j][nrow];
    *(u16x8*)&D[(size_t)(n0 + nrow) * dld + doff + k0 + k8 * 8] = o;
  }
}

__global__ __launch_bounds__(256) void bias_comb(
    const float* __restrict__ a, const float* __restrict__ b, float* __restrict__ o) {
  int i = blockIdx.x * 256 + threadIdx.x;
  o[i] = a[i] + b[i];
}

#define EPI_STORE 0
#define EPI_GELU 1
#define EPI_RES 2

// ---------------- GEMM v2: 8-wave phase-interleaved schedule (T3+T4+T5) ----------------
// Tile: (MSUB*32) x 256, BK=32, ring-4 LDS double^2 buffer, 512 threads = 8 waves (2M x 4N).
// LDS layout is FRAG-MAJOR: each 16x16x32 fragment = 64 contiguous lane-chunks of 16B, so
// every ds_read_b128 is base + lane*16 + imm  -> zero bank conflicts, zero read addr VALU.
// The fragment permutation is folded into the per-lane global_load_lds SOURCE address
// (LDS dest stays linear: rule #21 / m173 pattern).
// Staging leads 2 K-slots; s_waitcnt vmcnt(4|3) only at slot boundaries (T4: never 0 in loop).
// Raw s_barrier (NOT __syncthreads: that would re-insert the vmcnt(0) drain).

#define MMQ(Q)                                                                     \
  do {                                                                             \
    _Pragma("unroll") for (int mm_ = 0; mm_ < 4; ++mm_) {                          \
      _Pragma("unroll") for (int nn_ = 0; nn_ < 4; ++nn_)                          \
          acc[(Q) * 4 + mm_][nn_] = mfma16(af[mm_], bf[nn_], acc[(Q) * 4 + mm_][nn_]); \
    }                                                                              \
  } while (0)

#define SLOT(RR, RRS, S_)                                                          \
  do {                                                                             \
    const int s2_ = (S_) + 2;                                                      \
    const bool st_ = s2_ < nS;                                                     \
    short8 af[4], bf[4];                                                           \
    _Pragma("unroll") for (int f_ = 0; f_ < 4; ++f_)                               \
        af[f_] = *(const short8*)&Abuf[RR][awo + f_ * 512];                         \
    _Pragma("unroll") for (int f_ = 0; f_ < 4; ++f_)                               \
        bf[f_] = *(const short8*)&Bbuf[RR][bwo + f_ * 512];                         \
    if (st_) {                                                                     \
      gload16(gA + (size_t)s2_ * 32, &Abuf[RRS][wv * 512]);                        \
      if constexpr (MSUB == 8) {                                                   \
        gload16(gA + (size_t)s2_ * 32 + 128 * ldAs, &Abuf[RRS][(8 + wv) * 512]);   \
      } else {                                                                     \
        gload16(gB + (size_t)s2_ * 32, &Bbuf[RRS][wv * 512]);                      \
        gload16(gB + (size_t)s2_ * 32 + 128 * Ksz, &Bbuf[RRS][(8 + wv) * 512]);    \
      }                                                                            \
    }                                                                              \
    __builtin_amdgcn_s_barrier();                                                  \
    __builtin_amdgcn_s_setprio(1);                                                 \
    MMQ(0);                                                                        \
    __builtin_amdgcn_s_setprio(0);                                                 \
    if constexpr (MSUB == 8) {                                                     \
      __builtin_amdgcn_s_barrier();                                                \
      _Pragma("unroll") for (int f_ = 0; f_ < 4; ++f_)                             \
          af[f_] = *(const short8*)&Abuf[RR][awo + (4 + f_) * 512];                 \
      if (st_) {                                                                   \
        gload16(gB + (size_t)s2_ * 32, &Bbuf[RRS][wv * 512]);                      \
        gload16(gB + (size_t)s2_ * 32 + 128 * Ksz, &Bbuf[RRS][(8 + wv) * 512]);    \
      }                                                                            \
      __builtin_amdgcn_s_barrier();                                                \
      __builtin_amdgcn_s_setprio(1);                                               \
      MMQ(1);                                                                      \
      __builtin_amdgcn_s_setprio(0);                                               \
    }                                                                              \
    if (st_) {                                                                     \
      if constexpr (MSUB == 8) asm volatile("s_waitcnt vmcnt(4)" ::: "memory");    \
      else asm volatile("s_waitcnt vmcnt(3)" ::: "memory");                        \
    } else if ((S_) + 1 < nS) {                                                    \
      asm volatile("s_waitcnt vmcnt(0)" ::: "memory");                             \
    }                                                                              \
    __builtin_amdgcn_s_barrier();                                                  \
    __builtin_amdgcn_sched_barrier(0);                                             \
  } while (0)

template <int MSUB, int EPI, int OF32>
__global__ __launch_bounds__(512, 2) void gemm8(
    const unsigned short* __restrict__ A, const unsigned short* __restrict__ Bt,
    const float* __restrict__ bias, void* __restrict__ Cv,
    const float* __restrict__ res, int K, int ldA, int ldC, int lgnmt) {
  static_assert(MSUB == 8 || MSUB == 4, "MSUB must be 8 (BM=256) or 4 (BM=128)");
  __shared__ __attribute__((aligned(16))) unsigned short Abuf[4][MSUB * 1024];
  __shared__ __attribute__((aligned(16))) unsigned short Bbuf[4][8192];
  const int tid = threadIdx.x, lane = tid & 63, wv = tid >> 6;
  const int g = lane >> 4, r = lane & 15;
  const int wr = wv >> 2, wc = wv & 3;
  const int bid = blockIdx.x, nwg = gridDim.x;
  const int swz = (bid & 7) * (nwg >> 3) + (bid >> 3);  // XCD-aware (nwg % 8 == 0)
  const int mt = swz & ((1 << lgnmt) - 1), nt = swz >> lgnmt;
  const size_t arow0 = (size_t)mt * (MSUB * 32);
  const size_t brow0 = (size_t)nt * 256;
  const size_t Ksz = (size_t)K, ldAs = (size_t)ldA;
  // per-lane global source: fragment permutation folded in (row = fb*16 + r, k = g*8)
  const unsigned short* gA = A + (arow0 + (size_t)(wv * 16 + r)) * ldAs + g * 8;
  const unsigned short* gB = Bt + (brow0 + (size_t)(wv * 16 + r)) * Ksz + g * 8;
  const int awo = wr * (MSUB * 512) + lane * 8;
  const int bwo = wc * 2048 + lane * 8;
  const int nS = K >> 5;  // K % 128 == 0 for all call sites
  f32x4 acc[MSUB][4] = {};

  // prologue: stage slots 0 and 1
  gload16(gA, &Abuf[0][wv * 512]);
  if constexpr (MSUB == 8) gload16(gA + 128 * ldAs, &Abuf[0][(8 + wv) * 512]);
  gload16(gB, &Bbuf[0][wv * 512]);
  gload16(gB + 128 * Ksz, &Bbuf[0][(8 + wv) * 512]);
  gload16(gA + 32, &Abuf[1][wv * 512]);
  if constexpr (MSUB == 8) gload16(gA + 32 + 128 * ldAs, &Abuf[1][(8 + wv) * 512]);
  gload16(gB + 32, &Bbuf[1][wv * 512]);
  gload16(gB + 32 + 128 * Ksz, &Bbuf[1][(8 + wv) * 512]);
  if constexpr (MSUB == 8) asm volatile("s_waitcnt vmcnt(4)" ::: "memory");
  else                     asm volatile("s_waitcnt vmcnt(3)" ::: "memory");
  __builtin_amdgcn_s_barrier();
  __builtin_amdgcn_sched_barrier(0);

  for (int s4 = 0; s4 < nS; s4 += 4) {  // nS % 4 == 0 -> ring indices compile-time
    SLOT(0, 2, s4 + 0);
    SLOT(1, 3, s4 + 1);
    SLOT(2, 0, s4 + 2);
    SLOT(3, 1, s4 + 3);
  }

#pragma unroll
  for (int m = 0; m < MSUB; ++m) {
#pragma unroll
    for (int n = 0; n < 4; ++n) {
      const int col = (int)brow0 + wc * 64 + n * 16 + r;
      const float bv = bias[col];
#pragma unroll
      for (int i = 0; i < 4; ++i) {
        const size_t row = arow0 + wr * (MSUB * 16) + m * 16 + g * 4 + i;
        float v = acc[m][n][i] + bv;
        if (EPI == EPI_GELU) v = 0.5f * v * (1.f + erff(v * 0.70710678118f));
        if (EPI == EPI_RES) v += res[row * ldC + col];
        if (OF32) ((float*)Cv)[row * ldC + col] = v;
        else ((unsigned short*)Cv)[row * ldC + col] = f2b(v);
      }
    }
  }
}

// ---------------- Sliding-window attention: one wg per (b,h,qblock of 128) ----------------
// qkv layout: [8192][3072] bf16, q=cols 0..1023, k=1024..2047, v=2048..3071, head h at h*64.
__global__ __launch_bounds__(256) void swa_kernel(
    const unsigned short* __restrict__ qkv, unsigned short* __restrict__ outc) {
  __shared__ __attribute__((aligned(16))) unsigned short Ks[256 * 64];   // swizzled [s][e]
  __shared__ __attribute__((aligned(16))) unsigned short Vt[64 * 264];   // [e][s]
  __shared__ __attribute__((aligned(16))) unsigned short Ps[128 * 264];  // [r][s]
  __shared__ __attribute__((aligned(16))) float dn[128];
  const int bid = blockIdx.x;
  const int qb = bid & 31, h = (bid >> 5) & 15, b = bid >> 9;
  const long btok = (long)b * 4096;
  const long tok0 = btok + (long)qb * 128;
  const int tid = threadIdx.x, lane = tid & 63, wv = tid >> 6;
  const int g = lane >> 4, r = lane & 15;

#pragma unroll
  for (int i = 0; i < 8; ++i) {  // K stage: 16B chunks, chunk-XOR swizzle over 8 chunks/row
    int chunk = (wv * 8 + i) * 64 + lane;
    int s = chunk >> 3, cc = (chunk & 7) ^ (s & 7);
    long kt = tok0 - 128 + s; if (kt < btok) kt = btok;  // block 0: masked anyway
    gload16(&qkv[(size_t)kt * 3072 + 1024 + h * 64 + cc * 8], &Ks[(wv * 8 + i) * 512]);
  }
#pragma unroll
  for (int i = 0; i < 8; ++i) {  // V transposed stage
    int chunk = i * 256 + tid;
    int s = chunk >> 3, e8 = chunk & 7;
    long kt = tok0 - 128 + s; if (kt < btok) kt = btok;
    u16x8 u = *(const u16x8*)&qkv[(size_t)kt * 3072 + 2048 + h * 64 + e8 * 8];
#pragma unroll
    for (int j = 0; j < 8; ++j) Vt[(e8 * 8 + j) * 264 + s] = u[j];
  }
  short8 qf[2][2];  // Q frags direct from global
#pragma unroll
  for (int m = 0; m < 2; ++m)
#pragma unroll
    for (int kc = 0; kc < 2; ++kc)
      qf[m][kc] = *(const short8*)&qkv[(size_t)(tok0 + wv * 32 + m * 16 + r) * 3072 + h * 64 + kc * 32 + g * 8];
  __syncthreads();

  float rs[2][4] = {};
  for (int n = 0; n < 16; ++n) {
    const int srow = n * 16 + r;
    short8 kf0 = *(const short8*)&Ks[srow * 64 + ((g) ^ (srow & 7)) * 8];
    short8 kf1 = *(const short8*)&Ks[srow * 64 + ((4 + g) ^ (srow & 7)) * 8];
#pragma unroll
    for (int m = 0; m < 2; ++m) {
      f32x4 acc = {0.f, 0.f, 0.f, 0.f};
      acc = mfma16(qf[m][0], kf0, acc);
      acc = mfma16(qf[m][1], kf1, acc);
#pragma unroll
      for (int i = 0; i < 4; ++i) {
        int rr = wv * 32 + m * 16 + g * 4 + i;
        int ss = n * 16 + r;
        bool valid = (ss >= rr + 1) && (ss <= rr + 128) && (qb > 0 || ss >= 128);
        float p = valid ? __expf(acc[i] * 0.125f) : 0.f;  // scores small: no max-sub needed
        rs[m][i] += p;
        Ps[rr * 264 + ss] = f2b(p);
      }
    }
  }
#pragma unroll
  for (int m = 0; m < 2; ++m)
#pragma unroll
    for (int i = 0; i < 4; ++i) {
      float v = rs[m][i];
      v += __shfl_xor(v, 1); v += __shfl_xor(v, 2);
      v += __shfl_xor(v, 4); v += __shfl_xor(v, 8);
      if (r == i) dn[wv * 32 + m * 16 + g * 4 + i] = v;
    }
  __syncthreads();

  f32x4 oacc[2][4] = {};
  for (int sc = 0; sc < 8; ++sc) {
    short8 pf[2], vf[4];
#pragma unroll
    for (int m = 0; m < 2; ++m)
      pf[m] = *(const short8*)&Ps[(wv * 32 + m * 16 + r) * 264 + sc * 32 + g * 8];
#pragma unroll
    for (int n = 0; n < 4; ++n)
      vf[n] = *(const short8*)&Vt[(n * 16 + r) * 264 + sc * 32 + g * 8];
#pragma unroll
    for (int m = 0; m < 2; ++m)
#pragma unroll
      for (int n = 0; n < 4; ++n)
        oacc[m][n] = mfma16(pf[m], vf[n], oacc[m][n]);
  }
#pragma unroll
  for (int m = 0; m < 2; ++m) {
    f32x4 dv = *(const f32x4*)&dn[wv * 32 + m * 16 + g * 4];
#pragma unroll
    for (int n = 0; n < 4; ++n) {
      int col = h * 64 + n * 16 + r;
#pragma unroll
      for (int i = 0; i < 4; ++i) {
        size_t row = (size_t)(tok0 + wv * 32 + m * 16 + g * 4 + i);
        outc[row * 2048 + col] = f2b(oacc[m][n][i] / dv[i]);
      }
    }
  }
}

// ---------------- Linear attention pass 1: per-chunk KVt[f][e], kz[e] ----------------
__global__ __launch_bounds__(256) void lin_pass1(
    const unsigned short* __restrict__ qkv, float* __restrict__ KVt, float* __restrict__ kz) {
  __shared__ __attribute__((aligned(16))) unsigned short kf[128 * 72];
  __shared__ __attribute__((aligned(16))) unsigned short vs[128 * 72];
  const int bid = blockIdx.x;
  const int ch = bid & 31, h = (bid >> 5) & 15, b = bid >> 9;
  const size_t tok0 = (size_t)b * 4096 + (size_t)ch * 128;
  const int tid = threadIdx.x;
#pragma unroll
  for (int i = 0; i < 4; ++i) {
    int c = i * 256 + tid;
    int row = c >> 3, e8 = c & 7;
    u16x8 uk = *(const u16x8*)&qkv[(tok0 + row) * 3072 + 1024 + h * 64 + e8 * 8];
    u16x8 uv = *(const u16x8*)&qkv[(tok0 + row) * 3072 + 2048 + h * 64 + e8 * 8];
    u16x8 tk;
#pragma unroll
    for (int j = 0; j < 8; ++j) {
      float x = b2f(uk[j]);
      x = (x > 0.f) ? x : expm1f(x);  // elu
      tk[j] = f2b(x + 1.0001f);
    }
    *(u16x8*)&kf[row * 72 + e8 * 8] = tk;
    *(u16x8*)&vs[row * 72 + e8 * 8] = uv;
  }
  __syncthreads();
  const int e0 = (tid & 15) * 4, f0 = (tid >> 4) * 4;
  float acc[4][4] = {};
  for (int c = 0; c < 128; ++c) {
    u16x4 ku = *(const u16x4*)&kf[c * 72 + e0];
    u16x4 vu = *(const u16x4*)&vs[c * 72 + f0];
    float ke[4], vv[4];
#pragma unroll
    for (int j = 0; j < 4; ++j) { ke[j] = b2f(ku[j]); vv[j] = b2f(vu[j]); }
#pragma unroll
    for (int jf = 0; jf < 4; ++jf)
#pragma unroll
      for (int je = 0; je < 4; ++je)
        acc[jf][je] += vv[jf] * ke[je];
  }
  const size_t base = (size_t)bid * 4096;
#pragma unroll
  for (int jf = 0; jf < 4; ++jf) {
    f32x4 o = {acc[jf][0], acc[jf][1], acc[jf][2], acc[jf][3]};
    *(f32x4*)&KVt[base + (f0 + jf) * 64 + e0] = o;
  }
  if (tid < 64) {
    float s = 0.f;
    for (int c = 0; c < 128; ++c) s += b2f(kf[c * 72 + tid]);
    kz[(size_t)bid * 64 + tid] = s;
  }
}

// ---------------- pass 2: per (b,h) exclusive prefix over 32 chunks (in place) ----------------
__global__ __launch_bounds__(256) void lin_pass2(float* __restrict__ KVt, float* __restrict__ kz) {
  const int bh = blockIdx.x;
  const int tid = threadIdx.x;
  f32x4 run[4] = {};
  for (int ch = 0; ch < 32; ++ch) {
    const size_t base = ((size_t)bh * 32 + ch) * 4096;
#pragma unroll
    for (int i = 0; i < 4; ++i) {
      float* p = &KVt[base + (size_t)(i * 256 + tid) * 4];
      f32x4 c = *(f32x4*)p;
      *(f32x4*)p = run[i];
      run[i] += c;
    }
  }
  if (tid < 64) {
    float rz = 0.f;
    for (int ch = 0; ch < 32; ++ch) {
      float* p = &kz[((size_t)bh * 32 + ch) * 64 + tid];
      float c = *p; *p = rz; rz += c;
    }
  }
}

// ---------------- pass 3: o = (q@S_prev + tril(qk^T)@v) / (q.z_prev + rowsumA + 1e-6) ----------------
__global__ __launch_bounds__(256) void lin_pass3(
    const unsigned short* __restrict__ qkv, const float* __restrict__ KVt,
    const float* __restrict__ kz, unsigned short* __restrict__ outc) {
  __shared__ __attribute__((aligned(16))) unsigned short qf[128 * 72];
  __shared__ __attribute__((aligned(16))) unsigned short kf[128 * 72];
  __shared__ __attribute__((aligned(16))) unsigned short vt[64 * 136];
  __shared__ __attribute__((aligned(16))) unsigned short st[64 * 72];
  __shared__ __attribute__((aligned(16))) unsigned short am[128 * 136];
  __shared__ __attribute__((aligned(16))) float zs[64];
  __shared__ __attribute__((aligned(16))) float dnl[128];
  const int bid = blockIdx.x;
  const int ch = bid & 31, h = (bid >> 5) & 15, b = bid >> 9;
  const size_t tok0 = (size_t)b * 4096 + (size_t)ch * 128;
  const int tid = threadIdx.x, lane = tid & 63, wv = tid >> 6;
  const int g = lane >> 4, r = lane & 15;

#pragma unroll
  for (int i = 0; i < 4; ++i) {
    int c = i * 256 + tid;
    int row = c >> 3, e8 = c & 7;
    u16x8 uq = *(const u16x8*)&qkv[(tok0 + row) * 3072 + h * 64 + e8 * 8];
    u16x8 uk = *(const u16x8*)&qkv[(tok0 + row) * 3072 + 1024 + h * 64 + e8 * 8];
    u16x8 uv = *(const u16x8*)&qkv[(tok0 + row) * 3072 + 2048 + h * 64 + e8 * 8];
    u16x8 tq, tk;
#pragma unroll
    for (int j = 0; j < 8; ++j) {
      float x = b2f(uq[j]) * 0.125f;
      x = (x > 0.f) ? x : expm1f(x);
      tq[j] = f2b(x + 1.0001f);
      float y = b2f(uk[j]);
      y = (y > 0.f) ? y : expm1f(y);
      tk[j] = f2b(y + 1.0001f);
    }
    *(u16x8*)&qf[row * 72 + e8 * 8] = tq;
    *(u16x8*)&kf[row * 72 + e8 * 8] = tk;
#pragma unroll
    for (int j = 0; j < 8; ++j) vt[(e8 * 8 + j) * 136 + row] = uv[j];
  }
#pragma unroll
  for (int i = 0; i < 2; ++i) {  // S_prev^T (f-major) f32 -> bf16 LDS
    int idx = i * 256 + tid;
    int f = idx >> 3, e8 = idx & 7;
    f32x4 s0 = *(const f32x4*)&KVt[(size_t)bid * 4096 + f * 64 + e8 * 8];
    f32x4 s1 = *(const f32x4*)&KVt[(size_t)bid * 4096 + f * 64 + e8 * 8 + 4];
    u16x8 t;
#pragma unroll
    for (int j = 0; j < 4; ++j) { t[j] = f2b(s0[j]); t[4 + j] = f2b(s1[j]); }
    *(u16x8*)&st[f * 72 + e8 * 8] = t;
  }
  if (tid < 64) zs[tid] = kz[(size_t)bid * 64 + tid];
  __syncthreads();

  short8 aq[2][2];
#pragma unroll
  for (int m = 0; m < 2; ++m)
#pragma unroll
    for (int kc = 0; kc < 2; ++kc)
      aq[m][kc] = *(const short8*)&qf[(wv * 32 + m * 16 + r) * 72 + kc * 32 + g * 8];

  float rsA[2][4] = {};
  for (int n = 0; n < 8; ++n) {  // A = tril(qf @ kf^T), bf16 to LDS + rowsums
    short8 bk0 = *(const short8*)&kf[(n * 16 + r) * 72 + g * 8];
    short8 bk1 = *(const short8*)&kf[(n * 16 + r) * 72 + 32 + g * 8];
#pragma unroll
    for (int m = 0; m < 2; ++m) {
      f32x4 acc = {0.f, 0.f, 0.f, 0.f};
      acc = mfma16(aq[m][0], bk0, acc);
      acc = mfma16(aq[m][1], bk1, acc);
#pragma unroll
      for (int i = 0; i < 4; ++i) {
        int rr = wv * 32 + m * 16 + g * 4 + i;
        int cc = n * 16 + r;
        float v = (cc <= rr) ? acc[i] : 0.f;
        rsA[m][i] += v;
        am[rr * 136 + cc] = f2b(v);
      }
    }
  }
#pragma unroll
  for (int m = 0; m < 2; ++m)
#pragma unroll
    for (int i = 0; i < 4; ++i) {
      float v = rsA[m][i];
      v += __shfl_xor(v, 1); v += __shfl_xor(v, 2);
      v += __shfl_xor(v, 4); v += __shfl_xor(v, 8);
      if (r == i) dnl[wv * 32 + m * 16 + g * 4 + i] = v;
    }
  __syncthreads();

  if (tid < 128) {  // den = rowsumA + qf . z_prev
    float s = dnl[tid];
#pragma unroll
    for (int e = 0; e < 64; e += 4) {
      u16x4 qv = *(const u16x4*)&qf[tid * 72 + e];
      s += b2f(qv[0]) * zs[e] + b2f(qv[1]) * zs[e + 1] + b2f(qv[2]) * zs[e + 2] + b2f(qv[3]) * zs[e + 3];
    }
    dnl[tid] = s + 1e-6f;
  }

  f32x4 oac[2][4] = {};
#pragma unroll
  for (int kc = 0; kc < 2; ++kc) {  // num += qf @ S_prev
    short8 sf[4];
#pragma unroll
    for (int n = 0; n < 4; ++n) sf[n] = *(const short8*)&st[(n * 16 + r) * 72 + kc * 32 + g * 8];
#pragma unroll
    for (int m = 0; m < 2; ++m)
#pragma unroll
      for (int n = 0; n < 4; ++n)
        oac[m][n] = mfma16(aq[m][kc], sf[n], oac[m][n]);
  }
  for (int c4 = 0; c4 < 4; ++c4) {  // num += A @ v
    short8 pa[2], vb[4];
#pragma unroll
    for (int m = 0; m < 2; ++m)
      pa[m] = *(const short8*)&am[(wv * 32 + m * 16 + r) * 136 + c4 * 32 + g * 8];
#pragma unroll
    for (int n = 0; n < 4; ++n)
      vb[n] = *(const short8*)&vt[(n * 16 + r) * 136 + c4 * 32 + g * 8];
#pragma unroll
    for (int m = 0; m < 2; ++m)
#pragma unroll
      for (int n = 0; n < 4; ++n)
        oac[m][n] = mfma16(pa[m], vb[n], oac[m][n]);
  }
  __syncthreads();
#pragma unroll
  for (int m = 0; m < 2; ++m) {
    f32x4 dv = *(const f32x4*)&dnl[wv * 32 + m * 16 + g * 4];
#pragma unroll
    for (int n = 0; n < 4; ++n) {
      int col = 1024 + h * 64 + n * 16 + r;
#pragma unroll
      for (int i = 0; i < 4; ++i) {
        size_t row = tok0 + wv * 32 + m * 16 + g * 4 + i;
        outc[row * 2048 + col] = f2b(oac[m][n][i] / dv[i]);
      }
    }
  }
}

// ---------------- host ----------------
extern "C" void kernel_launch(void* const* d_in, const int* in_sizes, int n_in,
                              void* d_out, int out_size, void* d_ws, size_t ws_size,
                              hipStream_t stream) {
  (void)in_sizes; (void)n_in; (void)out_size; (void)ws_size;
  const float* x      = (const float*)d_in[0];
  const float* g1     = (const float*)d_in[1];
  const float* b1     = (const float*)d_in[2];
  const float* Wqkv_a = (const float*)d_in[3];
  const float* bqkv_a = (const float*)d_in[4];
  const float* Wp_a   = (const float*)d_in[5];
  const float* bp_a   = (const float*)d_in[6];
  const float* Wqkv_s = (const float*)d_in[7];
  const float* bqkv_s = (const float*)d_in[8];
  const float* Wo_s   = (const float*)d_in[9];
  const float* bo_s   = (const float*)d_in[10];
  const float* Wo     = (const float*)d_in[11];
  const float* bo     = (const float*)d_in[12];
  const float* gm     = (const float*)d_in[13];
  const float* bm     = (const float*)d_in[14];
  const float* W1     = (const float*)d_in[15];
  const float* b1m    = (const float*)d_in[16];
  const float* W2     = (const float*)d_in[17];
  const float* b2m    = (const float*)d_in[18];
  float* out = (float*)d_out;

  char* ws = (char*)d_ws;
  size_t off = 0;
  auto alloc = [&](size_t bytes) { char* p = ws + off; off += (bytes + 255) & ~(size_t)255; return p; };
  unsigned short* wTa   = (unsigned short*)alloc((size_t)3072 * 1024 * 2);
  unsigned short* wTs   = (unsigned short*)alloc((size_t)3072 * 1024 * 2);
  unsigned short* wTpo  = (unsigned short*)alloc((size_t)1024 * 2048 * 2);
  unsigned short* wTo   = (unsigned short*)alloc((size_t)1024 * 1024 * 2);
  unsigned short* wT1   = (unsigned short*)alloc((size_t)4096 * 1024 * 2);
  unsigned short* wT2   = (unsigned short*)alloc((size_t)1024 * 4096 * 2);
  float*          bcomb = (float*)alloc(1024 * 4);
  unsigned short* xn    = (unsigned short*)alloc((size_t)8192 * 1024 * 2);  // reused as h
  unsigned short* qkvA  = (unsigned short*)alloc((size_t)8192 * 3072 * 2);  // reused (w/ qkvS) as gbuf
  unsigned short* qkvS  = (unsigned short*)alloc((size_t)8192 * 3072 * 2);
  unsigned short* comb  = (unsigned short*)alloc((size_t)8192 * 2048 * 2);  // reused as x1 (f32)
  float*          kvt   = (float*)alloc((size_t)1024 * 4096 * 4);           // reused as sum (bf16)
  float*          kzp   = (float*)alloc((size_t)1024 * 64 * 4);
  unsigned short* gbuf  = qkvA;
  unsigned short* sum   = (unsigned short*)kvt;
  unsigned short* h_    = xn;
  float*          x1    = (float*)comb;  // comb dead once sum is computed

  transpose_w<<<dim3(16, 48), 256, 0, stream>>>(Wqkv_a, wTa, 3072, 1024, 0);
  transpose_w<<<dim3(16, 48), 256, 0, stream>>>(Wqkv_s, wTs, 3072, 1024, 0);
  transpose_w<<<dim3(16, 16), 256, 0, stream>>>(Wp_a, wTpo, 1024, 2048, 0);
  transpose_w<<<dim3(16, 16), 256, 0, stream>>>(Wo_s, wTpo, 1024, 2048, 1024);
  transpose_w<<<dim3(16, 16), 256, 0, stream>>>(Wo, wTo, 1024, 1024, 0);
  transpose_w<<<dim3(16, 64), 256, 0, stream>>>(W1, wT1, 4096, 1024, 0);
  transpose_w<<<dim3(64, 16), 256, 0, stream>>>(W2, wT2, 1024, 4096, 0);
  bias_comb<<<4, 256, 0, stream>>>(bp_a, bo_s, bcomb);

  ln_kernel<<<8192, 256, 0, stream>>>(x, g1, b1, xn);
  // M=8192, N=3072, K=1024: BM=256 -> grid 32x12=384
  gemm8<8, EPI_STORE, 0><<<384, 512, 0, stream>>>(xn, wTa, bqkv_a, qkvA, nullptr, 1024, 1024, 3072, 5);
  swa_kernel<<<1024, 256, 0, stream>>>(qkvA, comb);
  gemm8<8, EPI_STORE, 0><<<384, 512, 0, stream>>>(xn, wTs, bqkv_s, qkvS, nullptr, 1024, 1024, 3072, 5);
  lin_pass1<<<1024, 256, 0, stream>>>(qkvS, kvt, kzp);
  lin_pass2<<<32, 256, 0, stream>>>(kvt, kzp);
  lin_pass3<<<1024, 256, 0, stream>>>(qkvS, kvt, kzp, comb);
  // sum = [attn|ssm] @ [Wp_a;Wo_s] + (bp_a+bo_s): M=8192,N=1024,K=2048: BM=128 -> grid 64x4=256
  gemm8<4, EPI_STORE, 0><<<256, 512, 0, stream>>>(comb, wTpo, bcomb, sum, nullptr, 2048, 2048, 1024, 6);
  // x1 = x + sum @ Wo + bo   (f32 out)
  gemm8<4, EPI_RES, 1><<<256, 512, 0, stream>>>(sum, wTo, bo, x1, x, 1024, 1024, 1024, 6);
  ln_kernel<<<8192, 256, 0, stream>>>(x1, gm, bm, h_);
  // M=8192,N=4096,K=1024: BM=256 -> grid 32x16=512
  gemm8<8, EPI_GELU, 0><<<512, 512, 0, stream>>>(h_, wT1, b1m, gbuf, nullptr, 1024, 1024, 4096, 5);
  // M=8192,N=1024,K=4096: BM=128 -> grid 64x4=256
  gemm8<4, EPI_RES, 1><<<256, 512, 0, stream>>>(gbuf, wT2, b2m, out, x1, 4096, 4096, 1024, 6);
}